// Round 4
// baseline (354.834 us; speedup 1.0000x reference)
//
#include <hip/hip_runtime.h>
#include <math.h>

#define BSZ 128
#define KTOT 196608            // 3*256*256
#define NBLK1 256              // split-K blocks (1 per CU)
#define KC (KTOT / NBLK1)      // 768
#define BK 32                  // k per tile (one MFMA K-step)
#define NT (KC / BK)           // 24 tiles
#define REGF 0.01f
#define NITER 8                // contraction ~0.02/iter; converged ~1e-13 by iter 8

typedef short bf16x8 __attribute__((ext_vector_type(8)));
typedef float f32x4 __attribute__((ext_vector_type(4)));

__device__ __forceinline__ unsigned short f2bf(float f) {
    union { float f; unsigned int u; } x; x.f = f;
    unsigned int r = x.u + 0x7fffu + ((x.u >> 16) & 1u);   // RNE
    return (unsigned short)(r >> 16);
}

// async global->LDS, 16B per lane; dest = lds base (wave-uniform) + lane*16
__device__ __forceinline__ void gload16(const float* g, float* l) {
    __builtin_amdgcn_global_load_lds(
        (const __attribute__((address_space(1))) void*)g,
        (__attribute__((address_space(3))) void*)l, 16, 0, 0);
}

// Split-K bf16-MFMA GEMM with compiler-proof deep staging:
// raw fp32 slabs (imgs_w, imgs, target) go straight to LDS via
// global_load_lds (no VGPR round-trip, loads can't be sunk/serialized by
// regalloc -> 48 KB/CU guaranteed in flight). BK=32 double-buffered 2-phase:
// per tile {stage next buf (6 gloads/wave), compute cur buf, __syncthreads}.
// The syncthreads vmcnt(0) drain IS the T3 minimum-recipe per-tile wait.
// Bank-conflict fix: per-lane GLOBAL source pre-swizzle (chunk ^= row&7,
// LDS dest stays linear as gload_lds requires) + same XOR on read side.
// delta + bf16 convert happen at fragment-read time; norms from fragments.
__global__ __launch_bounds__(512, 2) void dot_kernel(
    const float* __restrict__ imgs, const float* __restrict__ imgs_w,
    const float* __restrict__ target, float* __restrict__ P,
    float* __restrict__ x2P, float* __restrict__ y2P)
{
    __shared__ float sW[2][BSZ * BK];   // imgs_w slab (raw fp32, swizzled chunks)
    __shared__ float sI[2][BSZ * BK];   // imgs slab
    __shared__ float sT[2][BSZ * BK];   // target slab
    const int t = threadIdx.x;
    const int bid = blockIdx.x;
    const long kbase = (long)bid * KC;

    const int lane = t & 63;
    const int wv = t >> 6;        // 8 waves
    const int fr = lane & 15;     // fragment row/col within 16-tile
    const int fq = lane >> 4;     // quad (k-slice)
    const int wrow0 = wv * 16;    // this wave's output-row block & staging rows

    // ---- staging geometry: wave wv stages rows wv*16..wv*16+15, 3 arrays ----
    // one gload16 covers 8 rows: lane l -> row sub l>>3, chunk slot l&7 (16B).
    // global pre-swizzle: slot (r, c) holds logical chunk c ^ (r&7).
    const int rr = lane >> 3;                 // 0..7
    const int cs = lane & 7;                  // 0..7
    const int swc = ((cs ^ rr) << 2);         // swizzled float offset in 32-float row
    const long g0 = (long)(wrow0 + rr) * KTOT + kbase + swc;
    const long g1 = (long)(wrow0 + 8 + rr) * KTOT + kbase + swc;
    const float* gw0 = imgs_w + g0;  const float* gw1 = imgs_w + g1;
    const float* gi0 = imgs + g0;    const float* gi1 = imgs + g1;
    const float* gt0 = target + g0;  const float* gt1 = target + g1;
    const int off0 = wrow0 * BK;              // LDS float offset of row block
    const int off1 = (wrow0 + 8) * BK;

#define STAGE(b, tl) do {                        \
    gload16(gw0 + (tl) * BK, &sW[b][off0]);      \
    gload16(gw1 + (tl) * BK, &sW[b][off1]);      \
    gload16(gi0 + (tl) * BK, &sI[b][off0]);      \
    gload16(gi1 + (tl) * BK, &sI[b][off1]);      \
    gload16(gt0 + (tl) * BK, &sT[b][off0]);      \
    gload16(gt1 + (tl) * BK, &sT[b][off1]);      \
} while (0)

    // ---- fragment-read geometry (XOR de-swizzle on the read side) ----
    const int abase = (wrow0 + fr) * BK;            // A row float base
    const int lo4 = (((2 * fq) ^ (fr & 7)) << 2);   // logical chunk 2fq
    const int hi4 = lo4 ^ 4;                        // logical chunk 2fq+1

    f32x4 acc[8];
#pragma unroll
    for (int ct = 0; ct < 8; ++ct) acc[ct] = (f32x4){0.f, 0.f, 0.f, 0.f};
    float x2a = 0.f, y2a = 0.f;

#define COMPUTE(cur) do {                                                      \
    const float* Wc = &sW[cur][0];                                             \
    const float* Ic = &sI[cur][0];                                             \
    const float* Tc = &sT[cur][0];                                             \
    const float4 wlo = *(const float4*)&Wc[abase + lo4];                       \
    const float4 whi = *(const float4*)&Wc[abase + hi4];                       \
    const float4 ulo = *(const float4*)&Ic[abase + lo4];                       \
    const float4 uhi = *(const float4*)&Ic[abase + hi4];                       \
    const float d0 = wlo.x - ulo.x, d1 = wlo.y - ulo.y;                        \
    const float d2 = wlo.z - ulo.z, d3 = wlo.w - ulo.w;                        \
    const float d4 = whi.x - uhi.x, d5 = whi.y - uhi.y;                        \
    const float d6 = whi.z - uhi.z, d7 = whi.w - uhi.w;                        \
    x2a += d0*d0 + d1*d1 + d2*d2 + d3*d3 + d4*d4 + d5*d5 + d6*d6 + d7*d7;      \
    bf16x8 af;                                                                 \
    af[0] = (short)f2bf(d0); af[1] = (short)f2bf(d1);                          \
    af[2] = (short)f2bf(d2); af[3] = (short)f2bf(d3);                          \
    af[4] = (short)f2bf(d4); af[5] = (short)f2bf(d5);                          \
    af[6] = (short)f2bf(d6); af[7] = (short)f2bf(d7);                          \
    _Pragma("unroll")                                                          \
    for (int ct = 0; ct < 8; ++ct) {                                           \
        const int bb = (ct * 16 + fr) * BK;                                    \
        const float4 tlo = *(const float4*)&Tc[bb + lo4];                      \
        const float4 thi = *(const float4*)&Tc[bb + hi4];                      \
        bf16x8 bf;                                                             \
        bf[0] = (short)f2bf(tlo.x); bf[1] = (short)f2bf(tlo.y);                \
        bf[2] = (short)f2bf(tlo.z); bf[3] = (short)f2bf(tlo.w);                \
        bf[4] = (short)f2bf(thi.x); bf[5] = (short)f2bf(thi.y);                \
        bf[6] = (short)f2bf(thi.z); bf[7] = (short)f2bf(thi.w);                \
        acc[ct] = __builtin_amdgcn_mfma_f32_16x16x32_bf16(af, bf, acc[ct], 0, 0, 0); \
        if (ct == wv)                                                          \
            y2a += tlo.x*tlo.x + tlo.y*tlo.y + tlo.z*tlo.z + tlo.w*tlo.w       \
                 + thi.x*thi.x + thi.y*thi.y + thi.z*thi.z + thi.w*thi.w;      \
    }                                                                          \
} while (0)

    // prologue: tile 0 -> buf 0; syncthreads drains vmcnt(0)
    STAGE(0, 0);
    __syncthreads();

#pragma unroll 1
    for (int tp = 0; tp < NT / 2; ++tp) {
        const int t0 = 2 * tp;
        STAGE(1, t0 + 1);          // next tile in flight during compute
        COMPUTE(0);
        __syncthreads();            // drains stage loads + all ds reads
        if (t0 + 2 < NT) STAGE(0, t0 + 2);
        COMPUTE(1);
        __syncthreads();
    }
#undef STAGE
#undef COMPUTE

    // norms: reduce the 4 k-slice lanes (fq groups) per row; rows unique/wave
    x2a += __shfl_xor(x2a, 16); x2a += __shfl_xor(x2a, 32);
    y2a += __shfl_xor(y2a, 16); y2a += __shfl_xor(y2a, 32);
    if (fq == 0) {
        x2P[bid * BSZ + wrow0 + fr] = x2a;
        y2P[bid * BSZ + wrow0 + fr] = y2a;
    }

    // store partial tile: C/D layout col=lane&15, row=quad*4+reg (m89/m91)
    float* Pb = P + ((size_t)bid << 14);
#pragma unroll
    for (int ct = 0; ct < 8; ++ct)
#pragma unroll
        for (int r = 0; r < 4; ++r)
            Pb[(wrow0 + fq * 4 + r) * BSZ + ct * 16 + fr] = acc[ct][r];
}

// Sum 256 partials (ILP-16), finish norms, build C = sqrt(relu(x2_i + y2_j - 2S)).
__global__ __launch_bounds__(256) void reduce_kernel(
    const float* __restrict__ P, const float* __restrict__ x2P,
    const float* __restrict__ y2P, float* __restrict__ C)
{
    __shared__ float y2loc[BSZ];
    __shared__ float x2loc[2];
    const int t = threadIdx.x;
    const int b = blockIdx.x;          // 64 blocks; rows {2b, 2b+1}
    if (t < 2) x2loc[t] = 0.f;
    __syncthreads();
    if (t < BSZ) {
        float s = 0.f;
#pragma unroll 8
        for (int bb = 0; bb < NBLK1; ++bb) s += y2P[bb * BSZ + t];
        y2loc[t] = s;
    } else {
        const int t2 = t - BSZ;
        const int rsel = t2 >> 6;       // 0/1
        const int part = t2 & 63;       // 64 threads x 4 blocks each
        const int row = 2 * b + rsel;
        float s = 0.f;
#pragma unroll
        for (int m = 0; m < 4; ++m) s += x2P[(part * 4 + m) * BSZ + row];
        atomicAdd(&x2loc[rsel], s);
    }
    __syncthreads();
    const int o = b * 256 + t;
    const int i = o >> 7, j = o & 127;
    float a[16];
#pragma unroll
    for (int m = 0; m < 16; ++m) a[m] = 0.f;
    for (int k0 = 0; k0 < NBLK1; k0 += 16) {
#pragma unroll
        for (int m = 0; m < 16; ++m) a[m] += P[(size_t)(k0 + m) * 16384 + o];
    }
    float s = 0.f;
#pragma unroll
    for (int m = 0; m < 16; ++m) s += a[m];
    C[o] = sqrtf(fmaxf(x2loc[i - 2 * b] + y2loc[j] - 2.f * s, 0.f));
}

// Single-block sinkhorn on prebuilt C; exp-factorized (two 128x128 matvecs/iter).
__global__ __launch_bounds__(1024) void sinkhorn_kernel(
    const float* __restrict__ Cg, float* __restrict__ out)
{
    __shared__ float C_lds[BSZ * BSZ];
    __shared__ float w_s[BSZ];           // exp(-v)
    __shared__ float g_s[BSZ];           // exp(-u)
    __shared__ float u_s[BSZ], v_s[BSZ];
    const int t = threadIdx.x;
    const int lane = t & 63;
    const int wave = t >> 6;
    const int rgrp = wave * 8 + (lane >> 3);
    const int off16 = (lane & 7) * 16;

#pragma unroll
    for (int q = 0; q < 4; ++q)
        *(float4*)&C_lds[q * 4096 + t * 4] = *(const float4*)&Cg[q * 4096 + t * 4];
    if (t < BSZ) w_s[t] = 1.f;
    __syncthreads();

    float rowE[16], colF[16], mrow, mcol;
    {
        float tmp[16]; float m = -1e30f;
#pragma unroll
        for (int k = 0; k < 16; ++k) { tmp[k] = C_lds[rgrp * BSZ + off16 + k]; m = fmaxf(m, tmp[k]); }
        m = fmaxf(m, __shfl_xor(m, 1)); m = fmaxf(m, __shfl_xor(m, 2)); m = fmaxf(m, __shfl_xor(m, 4));
        mrow = m;
#pragma unroll
        for (int k = 0; k < 16; ++k) rowE[k] = __expf(tmp[k] - mrow);
    }
    {
        float tmp[16]; float m = -1e30f;
#pragma unroll
        for (int k = 0; k < 16; ++k) { tmp[k] = C_lds[(off16 + k) * BSZ + rgrp]; m = fmaxf(m, tmp[k]); }
        m = fmaxf(m, __shfl_xor(m, 1)); m = fmaxf(m, __shfl_xor(m, 2)); m = fmaxf(m, __shfl_xor(m, 4));
        mcol = m;
#pragma unroll
        for (int k = 0; k < 16; ++k) colF[k] = __expf(tmp[k] - mcol);
    }

    const float log_ab = -logf(128.f);
    float u_cur = 0.f, v_cur = 0.f;

    for (int it = 0; it < NITER; ++it) {
        float acc = 0.f;
#pragma unroll
        for (int k = 0; k < 16; ++k) acc += rowE[k] * w_s[off16 + k];
        acc += __shfl_xor(acc, 1); acc += __shfl_xor(acc, 2); acc += __shfl_xor(acc, 4);
        const float lse = mrow + __logf(acc);
        u_cur = REGF * (log_ab - lse + u_cur);
        if ((lane & 7) == 0) g_s[rgrp] = __expf(-u_cur);
        __syncthreads();
        float acc2 = 0.f;
#pragma unroll
        for (int k = 0; k < 16; ++k) acc2 += colF[k] * g_s[off16 + k];
        acc2 += __shfl_xor(acc2, 1); acc2 += __shfl_xor(acc2, 2); acc2 += __shfl_xor(acc2, 4);
        const float lse2 = mcol + __logf(acc2);
        v_cur = REGF * (log_ab - lse2 + v_cur);
        if ((lane & 7) == 0) w_s[rgrp] = __expf(-v_cur);
        __syncthreads();
    }

    if ((lane & 7) == 0) { u_s[rgrp] = u_cur; v_s[rgrp] = v_cur; }
    __syncthreads();
    if (t == 0) {
        float su = 0.f;
        for (int i = 0; i < BSZ; ++i) su += u_s[i] + v_s[i];
        out[0] = su / 128.f;
    }
}

extern "C" void kernel_launch(void* const* d_in, const int* in_sizes, int n_in,
                              void* d_out, int out_size, void* d_ws, size_t ws_size,
                              hipStream_t stream) {
    const float* imgs   = (const float*)d_in[0];
    const float* imgs_w = (const float*)d_in[1];
    const float* target = (const float*)d_in[2];
    float* out = (float*)d_out;
    float* wsf = (float*)d_ws;

    float* P   = wsf;                                  // 256 * 16384 partials
    float* x2P = wsf + (size_t)NBLK1 * BSZ * BSZ;      // 256 * 128
    float* y2P = x2P + NBLK1 * BSZ;                    // 256 * 128
    float* C   = y2P + NBLK1 * BSZ;                    // 128 * 128

    dot_kernel<<<NBLK1, 512, 0, stream>>>(imgs, imgs_w, target, P, x2P, y2P);
    reduce_kernel<<<BSZ * BSZ / 256, 256, 0, stream>>>(P, x2P, y2P, C);
    sinkhorn_kernel<<<1, 1024, 0, stream>>>(C, out);
}